// Round 10
// baseline (785.160 us; speedup 1.0000x reference)
//
#include <hip/hip_runtime.h>
#include <math.h>

#define N_NODES 100000
#define N_EDGES 1600000
#define NCLS_ 40
#define NSCAN_BLOCKS ((N_NODES + 1023) / 1024)   // 98
#define DRANGE 12500                              // N_NODES / 8 XCD groups

typedef short bf16x8 __attribute__((ext_vector_type(8)));
typedef float f32x4 __attribute__((ext_vector_type(4)));

// bf16 helpers (RNE pack, exact unpack)
__device__ __forceinline__ unsigned short f2b(float f) {
    union { float f; unsigned u; } v; v.f = f;
    unsigned r = v.u + 0x7fffu + ((v.u >> 16) & 1u);
    return (unsigned short)(r >> 16);
}
__device__ __forceinline__ float2 up2(unsigned u) {   // packed pair -> floats
    union { unsigned u; float f; } a, b;
    a.u = u << 16; b.u = u & 0xffff0000u;
    return make_float2(a.f, b.f);
}
__device__ __forceinline__ unsigned pk2(float x, float y) {
    return (unsigned)f2b(x) | ((unsigned)f2b(y) << 16);
}
__device__ __forceinline__ float b2f(unsigned short s) {
    union { unsigned u; float f; } v; v.u = ((unsigned)s) << 16;
    return v.f;
}

// qkvs row layout (512 shorts):
//   [0,128)    Q, channel c at c
//   [128,384)  K/V interleaved 16B/lane: half-lane hl (0..31) owns shorts
//              128+8hl..128+8hl+7 = {K4hl..K4hl+3, V4hl..V4hl+3}
//   [384,512)  S (skip), channel c at 384+c

// ---------------------------------------------------------------- utils
__global__ void zero_i32_kernel(int* __restrict__ p, int n) {
    int i = blockIdx.x * blockDim.x + threadIdx.x;
    if (i < n) p[i] = 0;
}

// W preconvert: fp32 [L][128k][128col] -> bf16 B-fragment layout
// Wbf[l][mat][g][n][k], n=col within 64-group, k=0..127.  131072 shorts.
__global__ __launch_bounds__(256) void wconv_kernel(
    const float* __restrict__ Wq, const float* __restrict__ Wk,
    const float* __restrict__ Wv, const float* __restrict__ Ws,
    unsigned short* __restrict__ Wbf) {
    int tid = blockIdx.x * 256 + threadIdx.x;
    if (tid >= 131072) return;
    int k   = tid & 127;
    int n   = (tid >> 7) & 63;
    int g   = (tid >> 13) & 1;
    int mat = (tid >> 14) & 3;
    int l   = tid >> 16;
    const float* W = (mat == 0) ? Wq : (mat == 1) ? Wk : (mat == 2) ? Wv : Ws;
    Wbf[tid] = f2b(W[l * 16384 + k * 128 + g * 64 + n]);
}

// ---------------------------------------------------------------- CSR build
__global__ __launch_bounds__(256) void hist_kernel(
    const int* __restrict__ dst, int* __restrict__ deg) {
    int group = blockIdx.x & 7;
    int gblk  = blockIdx.x >> 3;
    int nblk  = gridDim.x >> 3;
    int lo = group * DRANGE, hi = lo + DRANGE;
    for (int i = gblk * 256 + threadIdx.x; i < N_EDGES; i += nblk * 256) {
        int d = dst[i];
        if (d >= lo && d < hi) atomicAdd(&deg[d], 1);
    }
}

__global__ __launch_bounds__(1024) void scan_block_kernel(
    const int* __restrict__ deg, int* __restrict__ rowptr, int* __restrict__ sums) {
    __shared__ int tmp[1024];
    int t = threadIdx.x;
    int i = blockIdx.x * 1024 + t;
    int v = (i < N_NODES) ? deg[i] : 0;
    tmp[t] = v;
    __syncthreads();
    for (int d = 1; d < 1024; d <<= 1) {
        int add = (t >= d) ? tmp[t - d] : 0;
        __syncthreads();
        tmp[t] += add;
        __syncthreads();
    }
    if (i < N_NODES) rowptr[i] = tmp[t] - v;
    if (t == 1023) sums[blockIdx.x] = tmp[1023];
}

__global__ __launch_bounds__(128) void scan_sums_kernel(int* __restrict__ sums) {
    __shared__ int tmp[128];
    int t = threadIdx.x;
    int v = (t < NSCAN_BLOCKS) ? sums[t] : 0;
    tmp[t] = v;
    __syncthreads();
    for (int d = 1; d < 128; d <<= 1) {
        int add = (t >= d) ? tmp[t - d] : 0;
        __syncthreads();
        tmp[t] += add;
        __syncthreads();
    }
    if (t < NSCAN_BLOCKS) sums[t] = tmp[t] - v;
}

__global__ void scan_add_kernel(int* __restrict__ rowptr, const int* __restrict__ sums,
                                int* __restrict__ cursor) {
    int i = blockIdx.x * blockDim.x + threadIdx.x;
    if (i < N_NODES) {
        int val = rowptr[i] + sums[i >> 10];
        rowptr[i] = val;
        cursor[i] = val;
    }
    if (i == 0) rowptr[N_NODES] = N_EDGES;
}

__global__ __launch_bounds__(256) void scatter_kernel(
    const int* __restrict__ src, const int* __restrict__ dst,
    int* __restrict__ cursor, int* __restrict__ srcs) {
    int group = blockIdx.x & 7;
    int gblk  = blockIdx.x >> 3;
    int nblk  = gridDim.x >> 3;
    int lo = group * DRANGE, hi = lo + DRANGE;
    for (int i = gblk * 256 + threadIdx.x; i < N_EDGES; i += nblk * 256) {
        int d = dst[i];
        if (d >= lo && d < hi) {
            int pos = atomicAdd(&cursor[d], 1);
            srcs[pos] = src[i];
        }
    }
}

// ---------------------------------------------------------------- QKVS GEMM (bf16 MFMA)
// One block per 64-row tile, all 512 cols.  B fragments are read DIRECTLY
// from L2-resident Wbf (128 KB bf16) — no Bs LDS staging, no per-group
// barriers.  R7 lesson: 8 __syncthreads/block each drained vmcnt(0)
// including the group's 16 scattered 2B stores -> all pipes <15% busy.
// Now: single barrier after As staging; 8 groups of load+MFMA+store
// pipeline freely; stores drain asynchronously at kernel end.
// B-frag load pattern: lane (ln,quad) reads 16 B at row c*16+ln, k-chunk
// quad*8 -> wave touches 16 rows x 64 B = 16 full lines per instr.
__global__ __launch_bounds__(256) void gemm_qkvs_kernel(
    const void* __restrict__ Ap, int a_is_bf16,
    const unsigned short* __restrict__ Wbf,   // this layer: [g8][64][128]
    const float* __restrict__ b0, const float* __restrict__ b1,
    const float* __restrict__ b2, const float* __restrict__ b3,
    unsigned short* __restrict__ out) {
    __shared__ unsigned short As[64][138];
    int t = threadIdx.x;
    int row0 = blockIdx.x * 64;

    if (a_is_bf16) {
        const unsigned short* A = (const unsigned short*)Ap;
        for (int i = 0; i < 8; ++i) {
            int idx = t + i * 256;
            int r = idx >> 5, k4 = (idx & 31) << 2;
            ushort4 v = make_ushort4(0, 0, 0, 0);
            if (row0 + r < N_NODES) v = *(const ushort4*)&A[(size_t)(row0 + r) * 128 + k4];
            *(ushort4*)&As[r][k4] = v;
        }
    } else {
        const float* A = (const float*)Ap;
        for (int i = 0; i < 8; ++i) {
            int idx = t + i * 256;
            int r = idx >> 5, k4 = (idx & 31) << 2;
            float4 v = make_float4(0.f, 0.f, 0.f, 0.f);
            if (row0 + r < N_NODES) v = *(const float4*)&A[(size_t)(row0 + r) * 128 + k4];
            ushort4 o;
            o.x = f2b(v.x); o.y = f2b(v.y); o.z = f2b(v.z); o.w = f2b(v.w);
            *(ushort4*)&As[r][k4] = o;
        }
    }
    __syncthreads();   // the ONLY barrier

    int wv = t >> 6, lane = t & 63;
    int ln = lane & 15, quad = lane >> 4;

    // A fragments for this wave (reused across all 8 groups)
    bf16x8 afr[4];
    for (int ks = 0; ks < 4; ++ks)
        afr[ks] = *(bf16x8*)&As[wv * 16 + ln][ks * 32 + quad * 8];

    #pragma unroll
    for (int g = 0; g < 8; ++g) {
        int mat = g >> 1;
        const float* bias = (mat == 0) ? b0 : (mat == 1) ? b1 : (mat == 2) ? b2 : b3;
        int cb = (g & 1) * 64;
        const unsigned short* Wg = Wbf + (size_t)g * 8192;

        f32x4 acc[4];
        for (int c = 0; c < 4; ++c) acc[c] = (f32x4){0.f, 0.f, 0.f, 0.f};
        for (int ks = 0; ks < 4; ++ks) {
            for (int c = 0; c < 4; ++c) {
                bf16x8 b = *(const bf16x8*)&Wg[(c * 16 + ln) * 128 + ks * 32 + quad * 8];
                acc[c] = __builtin_amdgcn_mfma_f32_16x16x32_bf16(afr[ks], b, acc[c], 0, 0, 0);
            }
        }

        // epilogue through the 16B-interleave position map (no barrier after)
        for (int c = 0; c < 4; ++c) {
            int colInMat = cb + c * 16 + ln;
            float bb = bias[colInMat];
            int pos;
            if (mat == 0)      pos = colInMat;
            else if (mat == 3) pos = 384 + colInMat;
            else               pos = 128 + ((colInMat >> 2) << 3) + ((mat == 2) ? 4 : 0) + (colInMat & 3);
            for (int r = 0; r < 4; ++r) {
                int row = row0 + wv * 16 + quad * 4 + r;
                if (row < N_NODES)
                    out[(size_t)row * 512 + pos] = f2b(acc[c][r] + bb);
            }
        }
    }
}

// ---------------------------------------------------------------- fused edge pass
// HALF-WAVE per edge, 8-edge unroll: 4 independent uint4 KV gathers in
// flight per lane (R9: 2 in flight left the miss path at 3.4 TB/s with
// VALU 65% — MLP-bound).  srcs loads hoisted & issued together.
__global__ __launch_bounds__(256) void edge_fused_kernel(
    const unsigned short* __restrict__ qkvs,
    const int* __restrict__ srcs, const int* __restrict__ rowptr,
    const float* __restrict__ gamma, const float* __restrict__ beta,
    unsigned short* __restrict__ hout) {
    int n = (blockIdx.x * 256 + threadIdx.x) >> 6;
    int lane = threadIdx.x & 63;
    if (n >= N_NODES) return;
    int half = lane >> 5, hl = lane & 31;
    const unsigned short* qrow = qkvs + (size_t)n * 512;
    uint2 qu = *(const uint2*)&qrow[4 * hl];
    float2 q01 = up2(qu.x), q23 = up2(qu.y);
    uint2 su = *(const uint2*)&qrow[384 + 4 * hl];
    float2 sk01 = up2(su.x), sk23 = up2(su.y);
    int e0 = rowptr[n], e1 = rowptr[n + 1];
    float a0 = 0.f, a1 = 0.f, a2 = 0.f, a3 = 0.f, dsum = 0.f;
    const float sc = 0.17677669529663687f;   // 1/sqrt(32)
    int idx = e0;
    for (; idx + 7 < e1; idx += 8) {
        int sA = srcs[idx + half];
        int sB = srcs[idx + 2 + half];
        int sC = srcs[idx + 4 + half];
        int sD = srcs[idx + 6 + half];
        uint4 kvA = *(const uint4*)&qkvs[(size_t)sA * 512 + 128 + 8 * hl];
        uint4 kvB = *(const uint4*)&qkvs[(size_t)sB * 512 + 128 + 8 * hl];
        uint4 kvC = *(const uint4*)&qkvs[(size_t)sC * 512 + 128 + 8 * hl];
        uint4 kvD = *(const uint4*)&qkvs[(size_t)sD * 512 + 128 + 8 * hl];
        float2 kA01 = up2(kvA.x), kA23 = up2(kvA.y);
        float2 kB01 = up2(kvB.x), kB23 = up2(kvB.y);
        float2 kC01 = up2(kvC.x), kC23 = up2(kvC.y);
        float2 kD01 = up2(kvD.x), kD23 = up2(kvD.y);
        float pA = q01.x * kA01.x + q01.y * kA01.y + q23.x * kA23.x + q23.y * kA23.y;
        float pB = q01.x * kB01.x + q01.y * kB01.y + q23.x * kB23.x + q23.y * kB23.y;
        float pC = q01.x * kC01.x + q01.y * kC01.y + q23.x * kC23.x + q23.y * kC23.y;
        float pD = q01.x * kD01.x + q01.y * kD01.y + q23.x * kD23.x + q23.y * kD23.y;
        pA += __shfl_xor(pA, 1); pB += __shfl_xor(pB, 1); pC += __shfl_xor(pC, 1); pD += __shfl_xor(pD, 1);
        pA += __shfl_xor(pA, 2); pB += __shfl_xor(pB, 2); pC += __shfl_xor(pC, 2); pD += __shfl_xor(pD, 2);
        pA += __shfl_xor(pA, 4); pB += __shfl_xor(pB, 4); pC += __shfl_xor(pC, 4); pD += __shfl_xor(pD, 4);
        float eA = __expf(pA * sc), eB = __expf(pB * sc);
        float eC = __expf(pC * sc), eD = __expf(pD * sc);
        float2 vA01 = up2(kvA.z), vA23 = up2(kvA.w);
        float2 vB01 = up2(kvB.z), vB23 = up2(kvB.w);
        float2 vC01 = up2(kvC.z), vC23 = up2(kvC.w);
        float2 vD01 = up2(kvD.z), vD23 = up2(kvD.w);
        a0 += eA * vA01.x + eB * vB01.x + eC * vC01.x + eD * vD01.x;
        a1 += eA * vA01.y + eB * vB01.y + eC * vC01.y + eD * vD01.y;
        a2 += eA * vA23.x + eB * vB23.x + eC * vC23.x + eD * vD23.x;
        a3 += eA * vA23.y + eB * vB23.y + eC * vC23.y + eD * vD23.y;
        dsum += (eA + eB) + (eC + eD);
    }
    for (; idx < e1; idx += 2) {
        int i = idx + half;
        bool valid = i < e1;
        int sA = srcs[valid ? i : e1 - 1];
        uint4 kvA = *(const uint4*)&qkvs[(size_t)sA * 512 + 128 + 8 * hl];
        float2 kA01 = up2(kvA.x), kA23 = up2(kvA.y);
        float pA = q01.x * kA01.x + q01.y * kA01.y + q23.x * kA23.x + q23.y * kA23.y;
        pA += __shfl_xor(pA, 1);
        pA += __shfl_xor(pA, 2);
        pA += __shfl_xor(pA, 4);
        float eA = valid ? __expf(pA * sc) : 0.f;
        float2 vA01 = up2(kvA.z), vA23 = up2(kvA.w);
        a0 += eA * vA01.x; a1 += eA * vA01.y;
        a2 += eA * vA23.x; a3 += eA * vA23.y;
        dsum += eA;
    }
    a0 += __shfl_xor(a0, 32); a1 += __shfl_xor(a1, 32);
    a2 += __shfl_xor(a2, 32); a3 += __shfl_xor(a3, 32);
    dsum += __shfl_xor(dsum, 32);
    float dinv = 1.0f / (dsum + 1e-16f);
    float o0 = a0 * dinv + sk01.x, o1 = a1 * dinv + sk01.y;
    float o2 = a2 * dinv + sk23.x, o3 = a3 * dinv + sk23.y;
    float sum = o0 + o1 + o2 + o3;
    for (int m = 1; m < 64; m <<= 1) sum += __shfl_xor(sum, m);
    float mu = sum * (1.0f / 256.0f);          // halves duplicated -> /256
    float d0 = o0 - mu, d1 = o1 - mu, d2 = o2 - mu, d3 = o3 - mu;
    float sq = d0 * d0 + d1 * d1 + d2 * d2 + d3 * d3;
    for (int m = 1; m < 64; m <<= 1) sq += __shfl_xor(sq, m);
    float rs = rsqrtf(sq * (1.0f / 256.0f) + 1e-5f);
    if (half == 0) {
        float4 g4 = *(const float4*)&gamma[4 * hl];
        float4 b4 = *(const float4*)&beta[4 * hl];
        float r0 = fmaxf(d0 * rs * g4.x + b4.x, 0.f);
        float r1 = fmaxf(d1 * rs * g4.y + b4.y, 0.f);
        float r2 = fmaxf(d2 * rs * g4.z + b4.z, 0.f);
        float r3 = fmaxf(d3 * rs * g4.w + b4.w, 0.f);
        uint2 w;
        w.x = pk2(r0, r1);
        w.y = pk2(r2, r3);
        *(uint2*)&hout[(size_t)n * 128 + 4 * hl] = w;
    }
}

// ---------------------------------------------------------------- classifier (h is bf16)
__global__ __launch_bounds__(256) void out_gemm_kernel(
    const unsigned short* __restrict__ h, const float* __restrict__ Wout,
    const float* __restrict__ bout, float* __restrict__ out) {
    __shared__ float hs[32][132];
    __shared__ float ws[128 * NCLS_];
    __shared__ float bsd[NCLS_];
    int t = threadIdx.x;
    int n0 = blockIdx.x * 32;
    for (int i = t; i < 128 * NCLS_; i += 256) ws[i] = Wout[i];
    if (t < NCLS_) bsd[t] = bout[t];
    for (int i = t; i < 1024; i += 256) {
        int r = i >> 5, k4 = (i & 31) << 2;
        float4 a = make_float4(0.f, 0.f, 0.f, 0.f);
        if (n0 + r < N_NODES) {
            ushort4 u = *(const ushort4*)&h[(size_t)(n0 + r) * 128 + k4];
            a = make_float4(b2f(u.x), b2f(u.y), b2f(u.z), b2f(u.w));
        }
        *(float4*)&hs[r][k4] = a;
    }
    __syncthreads();
    int r = t >> 3, j0 = (t & 7) * 5;
    float acc[5];
    for (int j = 0; j < 5; ++j) acc[j] = bsd[j0 + j];
    for (int k = 0; k < 128; ++k) {
        float a = hs[r][k];
        for (int j = 0; j < 5; ++j) acc[j] += a * ws[k * NCLS_ + j0 + j];
    }
    int n = n0 + r;
    if (n < N_NODES) {
        for (int j = 0; j < 5; ++j) out[(size_t)n * NCLS_ + j0 + j] = acc[j];
    }
}

// ---------------------------------------------------------------- launch
extern "C" void kernel_launch(void* const* d_in, const int* in_sizes, int n_in,
                              void* d_out, int out_size, void* d_ws, size_t ws_size,
                              hipStream_t stream) {
    const float* x    = (const float*)d_in[0];
    const int*   ei   = (const int*)d_in[1];
    const int*   src  = ei;
    const int*   dst  = ei + N_EDGES;
    const float* Wq   = (const float*)d_in[2];
    const float* bq   = (const float*)d_in[3];
    const float* Wk   = (const float*)d_in[4];
    const float* bk   = (const float*)d_in[5];
    const float* Wv   = (const float*)d_in[6];
    const float* bv   = (const float*)d_in[7];
    const float* Wsk  = (const float*)d_in[8];
    const float* bsk  = (const float*)d_in[9];
    const float* gmm  = (const float*)d_in[10];
    const float* bta  = (const float*)d_in[11];
    const float* Wout = (const float*)d_in[12];
    const float* bout = (const float*)d_in[13];
    float* outp = (float*)d_out;

    char* p = (char*)d_ws;
    auto carve = [&](size_t bytes) {
        char* r = p;
        p += (bytes + 255) & ~(size_t)255;
        return r;
    };
    unsigned short* qkvs = (unsigned short*)carve((size_t)N_NODES * 512 * 2);
    unsigned short* h    = (unsigned short*)carve((size_t)N_NODES * 128 * 2);
    unsigned short* Wbf  = (unsigned short*)carve((size_t)131072 * 2);
    int* deg     = (int*)carve((size_t)N_NODES * 4);
    int* rowptr  = (int*)carve((size_t)(N_NODES + 1) * 4);
    int* cursor  = (int*)carve((size_t)N_NODES * 4);
    int* srcs    = (int*)carve((size_t)N_EDGES * 4);
    int* sums    = (int*)carve((size_t)NSCAN_BLOCKS * 4);

    wconv_kernel<<<512, 256, 0, stream>>>(Wq, Wk, Wv, Wsk, Wbf);

    zero_i32_kernel<<<(N_NODES + 255) / 256, 256, 0, stream>>>(deg, N_NODES);
    hist_kernel<<<2048, 256, 0, stream>>>(dst, deg);
    scan_block_kernel<<<NSCAN_BLOCKS, 1024, 0, stream>>>(deg, rowptr, sums);
    scan_sums_kernel<<<1, 128, 0, stream>>>(sums);
    scan_add_kernel<<<(N_NODES + 255) / 256, 256, 0, stream>>>(rowptr, sums, cursor);
    scatter_kernel<<<2048, 256, 0, stream>>>(src, dst, cursor, srcs);

    for (int l = 0; l < 2; ++l) {
        const void* hin = l ? (const void*)h : (const void*)x;
        gemm_qkvs_kernel<<<(N_NODES + 63) / 64, 256, 0, stream>>>(
            hin, l, Wbf + (size_t)l * 65536,
            bq + l * 128, bk + l * 128, bv + l * 128, bsk + l * 128, qkvs);
        edge_fused_kernel<<<(N_NODES + 3) / 4, 256, 0, stream>>>(
            qkvs, srcs, rowptr, gmm + l * 128, bta + l * 128, h);
    }
    out_gemm_kernel<<<(N_NODES + 31) / 32, 256, 0, stream>>>(h, Wout, bout, outp);
}